// Round 3
// baseline (511.604 us; speedup 1.0000x reference)
//
#include <hip/hip_runtime.h>
#include <hip/hip_bf16.h>

#define N_Q 256
#define M_S 1024
#define DD 512
#define HH 512

typedef __attribute__((ext_vector_type(8))) short short8;
typedef __attribute__((ext_vector_type(8))) __bf16 bf16x8;
typedef __attribute__((ext_vector_type(16))) float f32x16;
typedef __attribute__((ext_vector_type(2))) __bf16 bf16x2;

union U8 { short8 s; bf16x8 b; };

__device__ __forceinline__ unsigned short f2bf(float f) {
  unsigned int u = __float_as_uint(f);
  u += 0x7FFFu + ((u >> 16) & 1u);
  return (unsigned short)(u >> 16);
}

__device__ __forceinline__ short8 pack8(const float* d) {
#if defined(__has_builtin) && __has_builtin(__builtin_amdgcn_cvt_pk_bf16_f32)
  short8 r;
#pragma unroll
  for (int i = 0; i < 4; ++i) {
    union { bf16x2 v; short s[2]; } u;
    u.v = __builtin_amdgcn_cvt_pk_bf16_f32(d[2 * i], d[2 * i + 1]);
    r[2 * i] = u.s[0];
    r[2 * i + 1] = u.s[1];
  }
  return r;
#else
  short8 r;
#pragma unroll
  for (int i = 0; i < 8; ++i) r[i] = (short)f2bf(d[i]);
  return r;
#endif
}

__device__ __forceinline__ short8 packdiff(float4 e0, float4 e1, float4 s0, float4 s1) {
  float d[8];
  d[0] = fabsf(e0.x - s0.x); d[1] = fabsf(e0.y - s0.y);
  d[2] = fabsf(e0.z - s0.z); d[3] = fabsf(e0.w - s0.w);
  d[4] = fabsf(e1.x - s1.x); d[5] = fabsf(e1.y - s1.y);
  d[6] = fabsf(e1.z - s1.z); d[7] = fabsf(e1.w - s1.w);
  return pack8(d);
}

// W1 [D][H] fp32 -> w1s: MFMA-B-fragment order ("flatmm" pre-shuffle).
// Frag f = kc*16 + h32 (kc: 16-wide k chunk, h32: 32-wide h chunk), 512 bf16:
// elem (lane l, j) = W1[k = kc*16 + (l>>5)*8 + j][h = h32*32 + (l&31)].
// Main kernel then loads each fragment as ONE coalesced 1024B read at base+lane*16.
__global__ __launch_bounds__(512) void prep_w1s(const float* __restrict__ W1,
                                                unsigned short* __restrict__ w1s) {
  const int f = blockIdx.x;            // 0..511
  const int kc = f >> 4, h32 = f & 15;
  const int l = threadIdx.x & 63, j = threadIdx.x >> 6;  // j wave-uniform
  const int h = h32 * 32 + (l & 31);
  const int k = kc * 16 + (l >> 5) * 8 + j;
  w1s[f * 512 + l * 8 + j] = f2bf(W1[k * HH + h]);
}

// Barrier-free fused kernel. Block = 512 thr = 8 waves; block tile 64 pairs x 512 h.
// Wave wid covers h in [wid*64, wid*64+64): acc[2 am][2 tj] of 32x32.
// A (diff) computed per-lane in registers; B loaded register-direct from w1s.
// Single __syncthreads at the epilogue for the cross-wave h-reduction.
__global__ __launch_bounds__(512, 2) void support_kernel(
    const float* __restrict__ emb, const float* __restrict__ sup,
    const unsigned short* __restrict__ w1s, const float* __restrict__ b1,
    const float* __restrict__ W2, const float* __restrict__ b2,
    float* __restrict__ out) {
  __shared__ float psums[64][8];

  const int tid = threadIdx.x;
  const int lane = tid & 63;
  const int wid = tid >> 6;        // 0..7 : h block of 64
  const int l31 = lane & 31;
  const int khalf = lane >> 5;

  const int m0 = blockIdx.x * 16;
  const int n0 = blockIdx.y * 4;

  // per-lane e/s row bases (A frag: row p = am*32 + l31, k = k0 + khalf*8 + j)
  const float* eb[2];
  const float* sb[2];
#pragma unroll
  for (int am = 0; am < 2; ++am) {
    const int p = am * 32 + l31;
    eb[am] = emb + (n0 + (p >> 4)) * DD + khalf * 8;
    sb[am] = sup + (m0 + (p & 15)) * DD + khalf * 8;
  }
  // B fragment base: frag (kc, tj in 0..1) at + (kc*16 + wid*2 + tj)*512 elems
  const unsigned short* bb = w1s + (wid * 2) * 512 + lane * 8;

  f32x16 acc[2][2] = {};

  U8 a[2][2];      // [am][kk]
  U8 b[2][2];      // [kk][tj]
  // prologue: load iter 0
#pragma unroll
  for (int am = 0; am < 2; ++am)
#pragma unroll
    for (int kk = 0; kk < 2; ++kk) {
      const float* ep = eb[am] + kk * 16;
      const float* sp = sb[am] + kk * 16;
      a[am][kk].s = packdiff(*(const float4*)ep, *(const float4*)(ep + 4),
                             *(const float4*)sp, *(const float4*)(sp + 4));
    }
#pragma unroll
  for (int kk = 0; kk < 2; ++kk)
#pragma unroll
    for (int tj = 0; tj < 2; ++tj)
      b[kk][tj].s = *(const short8*)(bb + (kk * 16 + tj) * 512);

#pragma unroll
  for (int it = 0; it < 16; ++it) {
    // ---- issue next iter's loads first (prefetch) ----
    float4 ev[2][2][2], sv[2][2][2];   // [am][kk][half]
    U8 bn[2][2];
    if (it < 15) {
      const int ko = (it + 1) * 32;
#pragma unroll
      for (int am = 0; am < 2; ++am)
#pragma unroll
        for (int kk = 0; kk < 2; ++kk) {
          const float* ep = eb[am] + ko + kk * 16;
          const float* sp = sb[am] + ko + kk * 16;
          ev[am][kk][0] = *(const float4*)ep;
          ev[am][kk][1] = *(const float4*)(ep + 4);
          sv[am][kk][0] = *(const float4*)sp;
          sv[am][kk][1] = *(const float4*)(sp + 4);
        }
#pragma unroll
      for (int kk = 0; kk < 2; ++kk)
#pragma unroll
        for (int tj = 0; tj < 2; ++tj)
          bn[kk][tj].s = *(const short8*)(bb + (((it + 1) * 2 + kk) * 16 + tj) * 512);
    }
    // ---- MFMA on current registers ----
#pragma unroll
    for (int kk = 0; kk < 2; ++kk)
#pragma unroll
      for (int am = 0; am < 2; ++am)
#pragma unroll
        for (int tj = 0; tj < 2; ++tj)
          acc[am][tj] = __builtin_amdgcn_mfma_f32_32x32x16_bf16(
              a[am][kk].b, b[kk][tj].b, acc[am][tj], 0, 0, 0);
    // ---- pack next A frags; rotate ----
    if (it < 15) {
#pragma unroll
      for (int am = 0; am < 2; ++am)
#pragma unroll
        for (int kk = 0; kk < 2; ++kk)
          a[am][kk].s = packdiff(ev[am][kk][0], ev[am][kk][1],
                                 sv[am][kk][0], sv[am][kk][1]);
#pragma unroll
      for (int kk = 0; kk < 2; ++kk)
#pragma unroll
        for (int tj = 0; tj < 2; ++tj)
          b[kk][tj] = bn[kk][tj];
    }
  }

  // ---- epilogue: per-wave partial over its 64 h, then cross-wave LDS reduce ----
  float b1v[2], w2v[2];
#pragma unroll
  for (int tj = 0; tj < 2; ++tj) {
    const int h = wid * 64 + tj * 32 + l31;   // C/D: col = lane&31
    b1v[tj] = b1[h];
    w2v[tj] = W2[h];
  }
#pragma unroll
  for (int am = 0; am < 2; ++am) {
#pragma unroll
    for (int r = 0; r < 16; ++r) {
      float s = fmaxf(acc[am][0][r] + b1v[0], 0.f) * w2v[0] +
                fmaxf(acc[am][1][r] + b1v[1], 0.f) * w2v[1];
      s += __shfl_xor(s, 1, 64);
      s += __shfl_xor(s, 2, 64);
      s += __shfl_xor(s, 4, 64);
      s += __shfl_xor(s, 8, 64);
      s += __shfl_xor(s, 16, 64);
      if (l31 == 0) {
        const int row32 = (r & 3) + 8 * (r >> 2) + 4 * khalf;  // C/D row map (m74/m101)
        psums[am * 32 + row32][wid] = s;
      }
    }
  }
  __syncthreads();
  if (tid < 64) {
    float t = b2[0];
#pragma unroll
    for (int w = 0; w < 8; ++w) t += psums[tid][w];
    const float sig = 1.f / (1.f + __expf(-t));
    out[(n0 + (tid >> 4)) * M_S + m0 + (tid & 15)] = sig;
  }
}

extern "C" void kernel_launch(void* const* d_in, const int* in_sizes, int n_in,
                              void* d_out, int out_size, void* d_ws, size_t ws_size,
                              hipStream_t stream) {
  const float* emb = (const float*)d_in[0];
  const float* sup = (const float*)d_in[1];
  const float* W1  = (const float*)d_in[2];
  const float* b1  = (const float*)d_in[3];
  const float* W2  = (const float*)d_in[4];
  const float* b2  = (const float*)d_in[5];
  float* out = (float*)d_out;
  unsigned short* w1s = (unsigned short*)d_ws;  // 512 KB fragment-ordered W1

  prep_w1s<<<512, 512, 0, stream>>>(W1, w1s);
  support_kernel<<<dim3(M_S / 16, N_Q / 4), 512, 0, stream>>>(
      emb, sup, w1s, b1, W2, b2, out);
}

// Round 4
// 231.199 us; speedup vs baseline: 2.2128x; 2.2128x over previous
//
#include <hip/hip_runtime.h>
#include <hip/hip_bf16.h>

#define N_Q 256
#define M_S 1024
#define DD 512
#define HH 512

typedef __attribute__((ext_vector_type(8))) short short8;
typedef __attribute__((ext_vector_type(8))) __bf16 bf16x8;
typedef __attribute__((ext_vector_type(16))) float f32x16;
typedef __attribute__((ext_vector_type(2))) __bf16 bf16x2;

union U8 { short8 s; bf16x8 b; };

__device__ __forceinline__ unsigned short f2bf(float f) {
  unsigned int u = __float_as_uint(f);
  u += 0x7FFFu + ((u >> 16) & 1u);
  return (unsigned short)(u >> 16);
}

__device__ __forceinline__ short8 pack8(const float* d) {
#if defined(__has_builtin) && __has_builtin(__builtin_amdgcn_cvt_pk_bf16_f32)
  short8 r;
#pragma unroll
  for (int i = 0; i < 4; ++i) {
    union { bf16x2 v; short s[2]; } u;
    u.v = __builtin_amdgcn_cvt_pk_bf16_f32(d[2 * i], d[2 * i + 1]);
    r[2 * i] = u.s[0];
    r[2 * i + 1] = u.s[1];
  }
  return r;
#else
  short8 r;
#pragma unroll
  for (int i = 0; i < 8; ++i) r[i] = (short)f2bf(d[i]);
  return r;
#endif
}

__device__ __forceinline__ short8 packdiff(float4 e0, float4 e1, float4 s0, float4 s1) {
  float d[8];
  d[0] = fabsf(e0.x - s0.x); d[1] = fabsf(e0.y - s0.y);
  d[2] = fabsf(e0.z - s0.z); d[3] = fabsf(e0.w - s0.w);
  d[4] = fabsf(e1.x - s1.x); d[5] = fabsf(e1.y - s1.y);
  d[6] = fabsf(e1.z - s1.z); d[7] = fabsf(e1.w - s1.w);
  return pack8(d);
}

// W1 [D][H] fp32 -> w1s in MFMA-B-fragment order (verified R3).
// Frag f = kc*16 + h32; elem (lane l, j) = W1[kc*16 + (l>>5)*8 + j][h32*32 + (l&31)].
__global__ __launch_bounds__(512) void prep_w1s(const float* __restrict__ W1,
                                                unsigned short* __restrict__ w1s) {
  const int f = blockIdx.x;            // 0..511
  const int kc = f >> 4, h32 = f & 15;
  const int l = threadIdx.x & 63, j = threadIdx.x >> 6;
  const int h = h32 * 32 + (l & 31);
  const int k = kc * 16 + (l >> 5) * 8 + j;
  w1s[f * 512 + l * 8 + j] = f2bf(W1[k * HH + h]);
}

// Block: 256 thr = 4 waves. Tile 64 pairs x 512 h x K=512.
// Full-K diff tile in LDS (64 KB), staged once -> K-loop has ZERO barriers.
// B register-direct from w1s (coalesced 16B/lane). 3 barriers total per block.
__global__ __launch_bounds__(256, 2) void support_kernel(
    const float* __restrict__ emb, const float* __restrict__ sup,
    const unsigned short* __restrict__ w1s, const float* __restrict__ b1,
    const float* __restrict__ W2, const float* __restrict__ b2,
    float* __restrict__ out) {
  __shared__ short As[64 * 512];  // 65536 B exactly; psums aliased after K-loop

  const int tid = threadIdx.x;
  const int lane = tid & 63;
  const int wid = tid >> 6;       // 0..3 : h-slice of 128
  const int l31 = lane & 31;
  const int khalf = lane >> 5;

  const int m0 = blockIdx.x * 16;
  const int n0 = blockIdx.y * 4;

  // ---- stage 64p x 512k diff tile; 16B chunks XOR-swizzled: c' = c ^ (p&7) ----
  // thread: c = tid&63 (k-chunk), pg = tid>>6 (n-row). Loop j over 16 m-rows.
  // e/s loads: lane-consecutive c -> coalesced full-row reads.
  // LDS writes: fixed row p per instr, c'=lane^const -> bank-balanced.
  {
    const int c = tid & 63;
    const int pg = tid >> 6;
    const float* e = emb + (n0 + pg) * DD + c * 8;
    const float4 e0 = *(const float4*)e;
    const float4 e1 = *(const float4*)(e + 4);
    const float* sp = sup + m0 * DD + c * 8;
#pragma unroll
    for (int j = 0; j < 16; ++j) {
      const float4 s0 = *(const float4*)(sp + j * DD);
      const float4 s1 = *(const float4*)(sp + j * DD + 4);
      const int p = pg * 16 + j;             // pair: n = n0+pg, m = m0+j
      *(short8*)&As[p * 512 + ((c ^ (j & 7)) * 8)] = packdiff(e0, e1, s0, s1);
    }
  }
  __syncthreads();  // barrier 1 of 3

  // ---- barrier-free K-loop: 32 steps of BK=16 ----
  const unsigned short* bb = w1s + (wid * 4) * 512 + lane * 8;  // frag base
  const int ar0 = l31 * 512;          // A row base, am=0 (shorts)
  const int ar1 = (32 + l31) * 512;   // am=1
  const int ax = l31 & 7;             // read-side chunk XOR

  f32x16 acc[2][4] = {};
  U8 a[2][2], b[2][4];

#pragma unroll
  for (int tj = 0; tj < 4; ++tj) b[0][tj].s = *(const short8*)(bb + tj * 512);
  {
    const int cc = (khalf ^ ax) * 8;  // step 0: chunk c = khalf
    a[0][0].s = *(const short8*)&As[ar0 + cc];
    a[0][1].s = *(const short8*)&As[ar1 + cc];
  }

#pragma unroll
  for (int kc = 0; kc < 32; ++kc) {
    const int cur = kc & 1, nxt = cur ^ 1;
    if (kc < 31) {  // 1-step register lookahead (A via LDS, B via global)
      const unsigned short* bp = bb + (kc + 1) * 16 * 512;
#pragma unroll
      for (int tj = 0; tj < 4; ++tj) b[nxt][tj].s = *(const short8*)(bp + tj * 512);
      const int cc = ((((kc + 1) * 2 + khalf)) ^ ax) * 8;
      a[nxt][0].s = *(const short8*)&As[ar0 + cc];
      a[nxt][1].s = *(const short8*)&As[ar1 + cc];
    }
#pragma unroll
    for (int tj = 0; tj < 4; ++tj) {
      acc[0][tj] = __builtin_amdgcn_mfma_f32_32x32x16_bf16(a[cur][0].b, b[cur][tj].b, acc[0][tj], 0, 0, 0);
      acc[1][tj] = __builtin_amdgcn_mfma_f32_32x32x16_bf16(a[cur][1].b, b[cur][tj].b, acc[1][tj], 0, 0, 0);
    }
  }

  // ---- epilogue: relu(C+b1)*W2, reduce over h; cross-wave via psums ----
  float b1v[4], w2v[4];
#pragma unroll
  for (int tj = 0; tj < 4; ++tj) {
    const int h = wid * 128 + tj * 32 + l31;  // C/D: col = lane&31
    b1v[tj] = b1[h];
    w2v[tj] = W2[h];
  }
  __syncthreads();  // barrier 2: all As reads done before aliasing
  float* psums = (float*)As;  // [64 pairs][4 waves]
#pragma unroll
  for (int am = 0; am < 2; ++am) {
#pragma unroll
    for (int r = 0; r < 16; ++r) {
      float s = 0.f;
#pragma unroll
      for (int tj = 0; tj < 4; ++tj)
        s += fmaxf(acc[am][tj][r] + b1v[tj], 0.f) * w2v[tj];
      s += __shfl_xor(s, 1, 64);
      s += __shfl_xor(s, 2, 64);
      s += __shfl_xor(s, 4, 64);
      s += __shfl_xor(s, 8, 64);
      s += __shfl_xor(s, 16, 64);
      if (l31 == 0) {
        const int row32 = (r & 3) + 8 * (r >> 2) + 4 * khalf;  // C/D row map (m74/m101)
        psums[(am * 32 + row32) * 4 + wid] = s;
      }
    }
  }
  __syncthreads();  // barrier 3
  if (tid < 64) {
    float t = psums[tid * 4] + psums[tid * 4 + 1] +
              psums[tid * 4 + 2] + psums[tid * 4 + 3] + b2[0];
    out[(n0 + (tid >> 4)) * M_S + m0 + (tid & 15)] = 1.f / (1.f + __expf(-t));
  }
}

extern "C" void kernel_launch(void* const* d_in, const int* in_sizes, int n_in,
                              void* d_out, int out_size, void* d_ws, size_t ws_size,
                              hipStream_t stream) {
  const float* emb = (const float*)d_in[0];
  const float* sup = (const float*)d_in[1];
  const float* W1  = (const float*)d_in[2];
  const float* b1  = (const float*)d_in[3];
  const float* W2  = (const float*)d_in[4];
  const float* b2  = (const float*)d_in[5];
  float* out = (float*)d_out;
  unsigned short* w1s = (unsigned short*)d_ws;  // 512 KB fragment-ordered W1

  prep_w1s<<<512, 512, 0, stream>>>(W1, w1s);
  support_kernel<<<dim3(M_S / 16, N_Q / 4), 256, 0, stream>>>(
      emb, sup, w1s, b1, W2, b2, out);
}